// Round 3
// baseline (28.993 us; speedup 1.0000x reference)
//
#include <hip/hip_runtime.h>

// Problem constants
#define N_MAX       128
#define NODE_VOCAB  128
#define EDGE_VOCAB  16
#define BATCH       256
#define SEQ         8256                   // N_MAX + N_MAX*(N_MAX-1)/2
#define N_EDGES     8128                   // SEQ - N_MAX

// Output layout (flat f32):
//   node_logits [B][N_MAX][NODE_VOCAB]   -> 256*128*128  = 4,194,304 floats
//   edge_logits [B][N_EDGES][EDGE_VOCAB] -> 256*8128*16  = 33,292,288 floats
#define NODE_FLOATS     (BATCH * N_MAX * NODE_VOCAB)
#define NODE_F_PER_B    (N_MAX * NODE_VOCAB)      // 16384 floats
#define EDGE_F_PER_B    (N_EDGES * EDGE_VOCAB)    // 130048 floats

// Per-batch float4 count: (16384 + 130048)/4 = 36608 = 143 * 256 exactly.
#define F4_PER_B        36608
#define NODE_F4_PER_B   4096                      // boundary: multiple of 256

// Native clang vector type — required by __builtin_nontemporal_store
// (HIP's float4 is a class and is rejected).
typedef float f32x4 __attribute__((ext_vector_type(4)));

__global__ __launch_bounds__(256)
void fill_logits_kernel(const int* __restrict__ x0,
                        float* __restrict__ out) {
    const int b = blockIdx.y;
    const int f = blockIdx.x * 256 + threadIdx.x;   // 0 .. 36607 (f4 index in batch)

    const int* __restrict__ xrow = x0 + (size_t)b * SEQ;

    int   x;       // target token for this row
    int   v0;      // first vocab index covered by this float4
    float* dst;    // destination (float4-aligned)

    if (f < NODE_F4_PER_B) {
        // node region: blocks 0..15 (wave-uniform branch)
        const int i = f >> 5;               // node slot 0..127
        v0  = (f & 31) << 2;                // vocab offset 0..124
        x   = xrow[i];
        dst = out + (size_t)b * NODE_F_PER_B + (size_t)f * 4;
    } else {
        // edge region: blocks 16..142
        const int g = f - NODE_F4_PER_B;    // 0 .. 32511
        const int j = g >> 2;               // edge slot 0..8127
        v0  = (g & 3) << 2;                 // vocab offset 0,4,8,12
        x   = xrow[N_MAX + j];
        dst = out + NODE_FLOATS + (size_t)b * EDGE_F_PER_B + (size_t)g * 4;
    }

    f32x4 v;
    v.x = (x == v0 + 0) ? 100.0f : -100.0f;
    v.y = (x == v0 + 1) ? 100.0f : -100.0f;
    v.z = (x == v0 + 2) ? 100.0f : -100.0f;
    v.w = (x == v0 + 3) ? 100.0f : -100.0f;

    // Output is write-once, never re-read: stream past L2 (nt flag) so the
    // x0 read stream keeps its cache lines and we avoid eviction traffic.
    __builtin_nontemporal_store(v, reinterpret_cast<f32x4*>(dst));
}

extern "C" void kernel_launch(void* const* d_in, const int* in_sizes, int n_in,
                              void* d_out, int out_size, void* d_ws, size_t ws_size,
                              hipStream_t stream) {
    const int* x0 = (const int*)d_in[0];   // [B, SEQ] int32 (harness-converted)
    float* out    = (float*)d_out;

    dim3 grid(F4_PER_B / 256, BATCH);      // (143, 256)
    fill_logits_kernel<<<grid, 256, 0, stream>>>(x0, out);
}